// Round 1
// 124.093 us; speedup vs baseline: 1.0144x; 1.0144x over previous
//
#include <hip/hip_runtime.h>

// QuantizedBKCore: tridiagonal resolvent diagonal via two continued-fraction
// sweeps, bit-exact vs numpy float32/complex64 reference (validated R1-R12:
// absmax == 0).
//
// R13 = R12 + 4-wave workgroups. R12's blocks were 64 threads = 1 wave; the
// CDNA 16-workgroups/CU cap then limits residency to 16 waves/CU = 50%
// occupancy (matches OccupancyPercent ~50-53), leaving 39% of VALU issue
// slots idle around the serial CF dependency chains. R13 packs 4 consecutive
// chunks of the same row into one 256-thread block sharing a single
// contiguous LDS stage (4*CHUNK + 2*HALO floats, interior halos merged,
// coalesced 256-wide staging, one barrier). 8 blocks/CU * 4 waves = 32
// waves/CU = 100% occupancy; grid = 512 rows * 4 = 2048 = exactly 8
// blocks/CU, one residency round. Per-lane math is byte-identical to R12
// (cheap rcp warmup 16 + exact Smith tail 8, fdiv_ieee Newton core, float4
// cc loads from zero-padded d_ws), so results stay bit-exact.

#define SEG    16                 // elements per lane
#define WCHEAP 16                 // approximate warmup steps (rcp-based)
#define WEXACT 8                  // exact Smith-tail steps
#define WARM   (WCHEAP + WEXACT)  // 24 total; HALO multiple of 4
#define LANES  64                 // lanes per wave
#define WAVES  4                  // waves (chunks) per block
#define NTHR   (LANES * WAVES)    // 256 threads per block
#define CHUNK  (LANES*SEG)        // 1024 elements per wave-chunk
#define BCHUNK (WAVES * CHUNK)    // 4096 elements per block
#define HALO   WARM
#define BSTAGE (BCHUNK + 2*HALO)  // 4144 staged negA values (shared halos)
#define SPAD   (BSTAGE + BSTAGE/32 + 1)  // stride-33 padding (2-way only: free)

struct C2 { float r, i; };

__device__ __forceinline__ int padi(int i) { return i + (i >> 5); }

// IEEE-correctly-rounded f32 divide for mid-range normal operands.
// Exactly the Newton core of LLVM's gfx9 fdiv expansion; div_scale/div_fixup
// are identity for den in [~0.7, 26], num <= 130 (all values arising here),
// so the result is bit-identical to the compiler's a/b (= numpy's divide).
__device__ __forceinline__ float fdiv_ieee(float num, float den) {
  const float r0 = __builtin_amdgcn_rcpf(den);
  const float e0 = __builtin_fmaf(-den, r0, 1.0f);
  const float r1 = __builtin_fmaf(e0, r0, r0);
  const float q0 = num * r1;
  const float e1 = __builtin_fmaf(-den, q0, num);
  const float q1 = __builtin_fmaf(e1, r1, q0);
  const float e2 = __builtin_fmaf(-den, q1, num);
  return __builtin_fmaf(e2, r1, q1);
}

// numpy CFLOAT_divide (Smith), numerator (nr, 0), no FMA contraction in the
// surrounding mul/add ops (explicit fmaf inside fdiv_ieee is intentional).
__device__ __forceinline__ C2 npdiv(float nr, float dr, float di) {
  #pragma clang fp contract(off)
  const bool  b   = fabsf(dr) >= fabsf(di);
  const float num = b ? di : dr;
  const float den = b ? dr : di;
  const float rat = fdiv_ieee(num, den);  // == IEEE num/den (range-proven)
  const float t   = num * rat;
  const float s   = den + t;              // mul + add, NOT fma
  const float scl = fdiv_ieee(1.0f, s);   // == IEEE 1/s
  const float u   = nr * scl;
  const float m   = nr * rat;
  const float w   = m * scl;
  C2 o;
  o.r = b ? u : w;
  o.i = b ? -w : -u;                      // sign-of-product flip is exact
  return o;
}

// exact continued-fraction step: carry <- cv / (z - a - carry), z = i
__device__ __forceinline__ void cf_step(float na, float cv, float& cr, float& ci) {
  #pragma clang fp contract(off)
  const float dr = na - cr;
  const float di = 1.0f - ci;
  const C2 nc = npdiv(cv, dr, di);
  cr = nc.r; ci = nc.i;
}

// cheap approximate step (warmup only, pre-merge): same map via rcp.
// cv=0 halo fakes stay bit-transparent: t=0 -> carry=(+-0,-+0).
__device__ __forceinline__ void cf_cheap(float na, float cv, float& cr, float& ci) {
  const float dr = na - cr;
  const float di = 1.0f - ci;
  const float m2 = dr * dr + di * di;         // in [1, ~130]
  const float r  = __builtin_amdgcn_rcpf(m2); // v_rcp_f32, ~1 ulp
  const float t  = cv * r;
  cr = dr * t;
  ci = -(di * t);
}

// -(clip(h0_diag + fake_quantize(v), -10, 10)); exact op order.
__device__ __forceinline__ float neg_a(float vv, float hd) {
  #pragma clang fp contract(off)
  float q = rintf(vv);                  // round half-even == np.rint
  q = fminf(fmaxf(q, -128.0f), 127.0f);
  float he = hd + q;
  he = fminf(fmaxf(he, -10.0f), 10.0f);
  return 0.0f - he;                     // Re(z - a)
}

// clip(+-100) -> rint -> clip(+-128); exact ops.
__device__ __forceinline__ float fq_out(float x) {
  #pragma clang fp contract(off)
  x = fminf(fmaxf(x, -100.0f), 100.0f);
  x = rintf(x);
  x = fminf(fmaxf(x, -128.0f), 127.0f);
  return x;
}

// ccf[i] = cc[i-HALO] zero-padded: i in [0, N + 2*HALO + 8)
__global__ void cc_kernel(const float* __restrict__ hsub,
                          const float* __restrict__ hsup,
                          float* __restrict__ ccf, int N) {
  #pragma clang fp contract(off)
  const int i = blockIdx.x * blockDim.x + threadIdx.x;
  if (i < N + 2*HALO + 8) {
    const int k = i - HALO;
    ccf[i] = (k >= 0 && k < N - 1) ? hsub[k] * hsup[k] : 0.0f;
  }
}

// w[0..7] = cc[m0..m0+7], where (m0+HALO) % 4 == 0: two aligned float4 loads.
__device__ __forceinline__ void load8_f(const float4* __restrict__ cc4,
                                        int m0, float* w) {
  const int q = (m0 + HALO) >> 2;
  const float4 A = cc4[q];
  const float4 B = cc4[q + 1];
  w[0]=A.x; w[1]=A.y; w[2]=A.z; w[3]=A.w;
  w[4]=B.x; w[5]=B.y; w[6]=B.z; w[7]=B.w;
}

// w[0..7] = cc[m0..m0+7], where (m0+HALO) % 4 == 3: three aligned float4 loads.
__device__ __forceinline__ void load8_b(const float4* __restrict__ cc4,
                                        int m0, float* w) {
  const int q = (m0 + HALO - 3) >> 2;   // (m0+HALO-3) % 4 == 0
  const float4 A = cc4[q];              // covers m0-3 .. m0
  const float4 B = cc4[q + 1];          // m0+1 .. m0+4
  const float4 C = cc4[q + 2];          // m0+5 .. m0+8
  w[0]=A.w;
  w[1]=B.x; w[2]=B.y; w[3]=B.z; w[4]=B.w;
  w[5]=C.x; w[6]=C.y; w[7]=C.z;
}

__global__ void __launch_bounds__(NTHR)
bk_kernel(const float* __restrict__ v,
          const float* __restrict__ hdiag,
          const float* __restrict__ ccf,      // zero-padded couplings (d_ws)
          float2* __restrict__ out,
          int N, int chunks_per_row, int blocks_per_row) {
  #pragma clang fp contract(off)
  __shared__ float sA[SPAD];            // negA for 4 chunks + halos: ~17.1 KB

  const int tid  = threadIdx.x;
  const int lane = tid & (LANES - 1);
  const int wv   = tid >> 6;
  const int row  = blockIdx.x / blocks_per_row;
  const int cb   = blockIdx.x - row * blocks_per_row;
  const int bbase = cb * BCHUNK;        // first element of the block's span
  const long rowoff = (long)row * N;
  const float4* cc4 = (const float4*)ccf;

  // ---- stage negA for all 4 chunks, 256-wide coalesced; zeros outside [0,N)
  for (int i = tid; i < BSTAGE; i += NTHR) {
    const int k = bbase - HALO + i;
    float na = 0.0f;
    if (k >= 0 && k < N) na = neg_a(v[rowoff + k], hdiag[k]);
    sA[padi(i)] = na;
  }
  __syncthreads();

  const int chunk = cb * WAVES + wv;
  if (chunk < chunks_per_row) {
    const int base = bbase + wv * CHUNK;  // this wave's chunk start
    const int s0  = base + lane * SEG;
    const int s1  = s0 + SEG;
    const int loff = bbase - HALO;        // global index of sA[0]
    const int li0 = s0 - loff;            // sA (unpadded) index of s0

    float Rr[SEG], Ri[SEG];
    float crB, ciB;                       // backward carry (R)
    float crF, ciF;                       // forward-warmup carry (L)
    float wcB[8], wcF[8];

    // ---- paired warmups (independent chains, interleaved for ILP) ---------
    // bwd: R[k-1] = cc[k-1] / (z - a[k] - R[k]), k = s1+23 .. s1, carry 0.
    // fwd: L[k+1] = cc[k]   / (z - a[k] - L[k]), k = s0-24 .. s0-1, carry 0.
    // Groups g=0,1: cheap rcp steps (pre-merge). g=2: exact Smith tail.
    crB = 0.0f; ciB = 0.0f; crF = 0.0f; ciF = 0.0f;
    #pragma unroll
    for (int g = 0; g < WARM / 8; ++g) {
      const int kh = s1 + (WARM - 1) - 8 * g;   // bwd group high k
      const int kl = s0 - WARM + 8 * g;         // fwd group low k
      load8_b(cc4, kh - 8, wcB);                // wcB[j'] = cc[kh-8+j']
      load8_f(cc4, kl, wcF);                    // wcF[j]  = cc[kl+j]
      #pragma unroll
      for (int j = 0; j < 8; ++j) {
        const float naB = sA[padi(kh - j - loff)];
        const float naF = sA[padi(kl + j - loff)];
        if (g < (WCHEAP / 8)) {                 // cheap phase
          cf_cheap(naB, wcB[7 - j], crB, ciB);  // cc[k-1], k = kh-j
          cf_cheap(naF, wcF[j],     crF, ciF);  // cc[k],   k = kl+j
        } else {                                // exact Smith tail
          cf_step(naB, wcB[7 - j], crB, ciB);
          cf_step(naF, wcF[j],     crF, ciF);
        }
      }
    }
    Rr[SEG-1] = crB; Ri[SEG-1] = ciB;           // R[s1-1]

    // ---- backward main: t = SEG-1 .. 1, store R ---------------------------
    #pragma unroll
    for (int tg = 0; tg < SEG / 8; ++tg) {
      const int th = SEG - 1 - 8 * tg;          // high t of this group
      load8_b(cc4, s0 + th - 8, wcB);           // wcB[j'] = cc[s0+th-8+j']
      #pragma unroll
      for (int j = 0; j < 8; ++j) {
        const int t = th - j;
        if (t >= 1) {
          const float na = sA[padi(li0 + t)];
          cf_step(na, wcB[7 - j], crB, ciB);    // cc[k-1], k = s0+t
          Rr[t-1] = crB; Ri[t-1] = ciB;
        }
      }
    }

    // ---- forward main: combine with R, store G, advance L -----------------
    // (combine-npdiv and advance-npdiv are mutually independent: 2-wide ILP)
    #pragma unroll
    for (int tg = 0; tg < SEG / 8; ++tg) {
      const int kl = s0 + 8 * tg;
      load8_f(cc4, kl, wcF);                    // wcF[j] = cc[kl+j]
      #pragma unroll
      for (int j = 0; j < 8; ++j) {
        const int t = 8 * tg + j;
        const float na  = sA[padi(li0 + t)];
        const float drL = na - crF;             // (z - a) - L
        const float diL = 1.0f - ciF;
        const float drf = drL - Rr[t];          // ... - R
        const float dif = diL - Ri[t];
        const C2 G = npdiv(1.0f, drf, dif);
        out[rowoff + kl + j] = make_float2(fq_out(G.r), fq_out(G.i));
        if (t < SEG - 1) {                      // advance L within segment
          const C2 nc = npdiv(wcF[j], drL, diL);
          crF = nc.r; ciF = nc.i;
        }
      }
    }
  }
}

extern "C" void kernel_launch(void* const* d_in, const int* in_sizes, int n_in,
                              void* d_out, int out_size, void* d_ws, size_t ws_size,
                              hipStream_t stream) {
  const float* v    = (const float*)d_in[0];
  const float* hd   = (const float*)d_in[1];
  const float* hsub = (const float*)d_in[2];
  const float* hsup = (const float*)d_in[3];
  const int N = in_sizes[1];
  const int B = in_sizes[0] / N;
  const int chunks = (N + CHUNK - 1) / CHUNK;        // 16 for N=16384 (exact)
  const int bpr    = (chunks + WAVES - 1) / WAVES;   // 4 blocks per row

  float* ccf = (float*)d_ws;                     // N + 2*HALO + 8 floats
  const int ccn = N + 2*HALO + 8;
  cc_kernel<<<(ccn + 255) / 256, 256, 0, stream>>>(hsub, hsup, ccf, N);
  bk_kernel<<<B * bpr, NTHR, 0, stream>>>(v, hd, ccf, (float2*)d_out,
                                          N, chunks, bpr);
}